// Round 1
// baseline (2410.701 us; speedup 1.0000x reference)
//
#include <hip/hip_runtime.h>
#include <hip/hip_bf16.h>

#define TSTEPS 60
#define HIDDEN 64

// One thread per sample. Sequential recurrence over TSTEPS with delta feedback.
// Layer-2 is k-outer so W2 row reads are wave-uniform -> scalar (s_load) path,
// inner j loop is pure v_fmac_f32 with SGPR weight operand.
__global__ __launch_bounds__(256)
void ffn_recurrent_f32(const float* __restrict__ feat,
                       const float* __restrict__ W1, const float* __restrict__ b1,
                       const float* __restrict__ W2, const float* __restrict__ b2,
                       const float* __restrict__ W3, const float* __restrict__ b3,
                       float* __restrict__ out, int N) {
    const int n = blockIdx.x * blockDim.x + threadIdx.x;
    if (n >= N) return;

    const float* f = feat + (size_t)n * TSTEPS * 3;
    float* o = out + (size_t)n * TSTEPS;

    float delta = 0.0f;
    float h1[HIDDEN];
    float h2[HIDDEN];

    for (int t = 0; t < TSTEPS; ++t) {
        const float x0 = f[3 * t + 0];
        const float x1 = f[3 * t + 1];
        const float x2 = f[3 * t + 2];
        const float x3 = delta;

        // Layer 1: h1 = relu(x @ W1 + b1); W1 is (4, 64) row-major.
#pragma unroll
        for (int j = 0; j < HIDDEN; ++j) {
            float a = b1[j];
            a = fmaf(x0, W1[0 * HIDDEN + j], a);
            a = fmaf(x1, W1[1 * HIDDEN + j], a);
            a = fmaf(x2, W1[2 * HIDDEN + j], a);
            a = fmaf(x3, W1[3 * HIDDEN + j], a);
            h1[j] = fmaxf(a, 0.0f);
        }

        // Layer 2: h2 = h1 @ W2 + b2 (relu deferred into layer 3).
        // k-outer: each k reads W2 row k (contiguous, wave-uniform address).
#pragma unroll
        for (int j = 0; j < HIDDEN; ++j) h2[j] = b2[j];
        for (int k = 0; k < HIDDEN; ++k) {
            const float hk = h1[k];
            const float* w2row = W2 + k * HIDDEN;
#pragma unroll
            for (int j = 0; j < HIDDEN; ++j) {
                h2[j] = fmaf(hk, w2row[j], h2[j]);
            }
        }

        // Layer 3: delta = relu(h2) @ W3 + b3; W3 is (64, 1).
        float d = b3[0];
#pragma unroll
        for (int k = 0; k < HIDDEN; ++k) {
            d = fmaf(fmaxf(h2[k], 0.0f), W3[k], d);
        }
        delta = d;
        o[t] = delta;
    }
}

extern "C" void kernel_launch(void* const* d_in, const int* in_sizes, int n_in,
                              void* d_out, int out_size, void* d_ws, size_t ws_size,
                              hipStream_t stream) {
    const float* feat = (const float*)d_in[0];
    const float* W1   = (const float*)d_in[1];
    const float* b1   = (const float*)d_in[2];
    const float* W2   = (const float*)d_in[3];
    const float* b2   = (const float*)d_in[4];
    const float* W3   = (const float*)d_in[5];
    const float* b3   = (const float*)d_in[6];
    float* out = (float*)d_out;

    const int N = in_sizes[0] / (TSTEPS * 3);

    const int block = 256;
    const int grid = (N + block - 1) / block;
    ffn_recurrent_f32<<<grid, block, 0, stream>>>(feat, W1, b1, W2, b2, W3, b3, out, N);
}

// Round 2
// 2262.430 us; speedup vs baseline: 1.0655x; 1.0655x over previous
//
#include <hip/hip_runtime.h>
#include <hip/hip_bf16.h>

#define TSTEPS 60
#define HIDDEN 64

// Tiny prep kernel: W2T[j][k] = W2[k][j] so the main kernel's j-outer loop
// reads contiguous wave-uniform rows (s_load_dwordx16 path).
__global__ void transpose_w2(const float* __restrict__ W2, float* __restrict__ W2T) {
    const int i = threadIdx.x + blockIdx.x * blockDim.x;  // 4096 elems
    if (i < HIDDEN * HIDDEN) {
        const int j = i / HIDDEN, k = i % HIDDEN;
        W2T[j * HIDDEN + k] = W2[k * HIDDEN + j];
    }
}

// One thread per sample. All per-sample state in registers:
//  - h1[64] fully constant-indexed (unrolled) -> VGPRs, no scratch.
//  - layers 2+3 fused: per hidden unit j (wave-uniform rolled loop), dot
//    h1 . W2T[j] with 4 independent FMA chains, relu, FMA into delta acc.
__global__ __launch_bounds__(256)
void ffn_recurrent_f32(const float* __restrict__ feat,
                       const float* __restrict__ W1, const float* __restrict__ b1,
                       const float* __restrict__ W2T, const float* __restrict__ b2,
                       const float* __restrict__ W3, const float* __restrict__ b3,
                       float* __restrict__ out, int N) {
    const int n = blockIdx.x * blockDim.x + threadIdx.x;
    if (n >= N) return;

    const float* f = feat + (size_t)n * TSTEPS * 3;
    float* o = out + (size_t)n * TSTEPS;

    const float b3v = b3[0];
    float delta = 0.0f;
    float h1[HIDDEN];

    for (int t = 0; t < TSTEPS; ++t) {
        const float x0 = f[3 * t + 0];
        const float x1 = f[3 * t + 1];
        const float x2 = f[3 * t + 2];
        const float x3 = delta;

        // Layer 1: h1 = relu(x @ W1 + b1); W1 is (4, 64) row-major.
#pragma unroll
        for (int j = 0; j < HIDDEN; ++j) {
            float a = b1[j];
            a = fmaf(x0, W1[0 * HIDDEN + j], a);
            a = fmaf(x1, W1[1 * HIDDEN + j], a);
            a = fmaf(x2, W1[2 * HIDDEN + j], a);
            a = fmaf(x3, W1[3 * HIDDEN + j], a);
            h1[j] = fmaxf(a, 0.0f);
        }

        // Layers 2+3 fused: delta = sum_j relu(h1 . W2T[j] + b2[j]) * W3[j] + b3.
        float d = b3v;
#pragma unroll 2
        for (int j = 0; j < HIDDEN; ++j) {
            const float* __restrict__ w = W2T + j * HIDDEN;  // wave-uniform row
            float a0 = b2[j], a1 = 0.0f, a2 = 0.0f, a3 = 0.0f;
#pragma unroll
            for (int k = 0; k < HIDDEN; k += 4) {
                a0 = fmaf(h1[k + 0], w[k + 0], a0);
                a1 = fmaf(h1[k + 1], w[k + 1], a1);
                a2 = fmaf(h1[k + 2], w[k + 2], a2);
                a3 = fmaf(h1[k + 3], w[k + 3], a3);
            }
            const float a = (a0 + a1) + (a2 + a3);
            d = fmaf(fmaxf(a, 0.0f), W3[j], d);
        }
        delta = d;
        o[t] = delta;
    }
}

extern "C" void kernel_launch(void* const* d_in, const int* in_sizes, int n_in,
                              void* d_out, int out_size, void* d_ws, size_t ws_size,
                              hipStream_t stream) {
    const float* feat = (const float*)d_in[0];
    const float* W1   = (const float*)d_in[1];
    const float* b1   = (const float*)d_in[2];
    const float* W2   = (const float*)d_in[3];
    const float* b2   = (const float*)d_in[4];
    const float* W3   = (const float*)d_in[5];
    const float* b3   = (const float*)d_in[6];
    float* out = (float*)d_out;
    float* W2T = (float*)d_ws;  // 64*64*4 = 16 KB scratch

    const int N = in_sizes[0] / (TSTEPS * 3);

    transpose_w2<<<(HIDDEN * HIDDEN + 255) / 256, 256, 0, stream>>>(W2, W2T);

    const int block = 256;
    const int grid = (N + block - 1) / block;
    ffn_recurrent_f32<<<grid, block, 0, stream>>>(feat, W1, b1, W2T, b2, W3, b3, out, N);
}

// Round 3
// 294.081 us; speedup vs baseline: 8.1974x; 7.6932x over previous
//
#include <hip/hip_runtime.h>
#include <hip/hip_bf16.h>

#define TSTEPS 60
#define HIDDEN 64

typedef __attribute__((ext_vector_type(8))) short bf16x8;
typedef __attribute__((ext_vector_type(4))) float f32x4;

__device__ __forceinline__ short f2bf(float f) {
    return __builtin_bit_cast(short, __float2bfloat16(f));
}

// One wave = 16 samples, sequential over TSTEPS.
// All matrices kept "feature-major x sample-column":
//   L1: D1 = W1^T(64x4,K-pad32) @ x(4x16)      -> h1 (64x16)
//   L2: D2 = W2^T(64x64)        @ h1(64x16)    -> h2 (64x16)
//   L3: delta = relu(h2) . W3  (VALU dot + shfl_xor reduce)
// D-frag: col=lane&15 (sample), row=(lane>>4)*4+reg.  A/B-frags: 8 contig k per lane.
__global__ __launch_bounds__(256)
void ffn_mfma(const float* __restrict__ feat,
              const float* __restrict__ W1, const float* __restrict__ b1,
              const float* __restrict__ W2, const float* __restrict__ b2,
              const float* __restrict__ W3, const float* __restrict__ b3,
              float* __restrict__ out, int N) {
    __shared__ short h1s[4][1024];          // per-wave 16x64 bf16, swizzled
    __shared__ float dlt[4][16 * TSTEPS];   // per-wave output staging

    const int lane = threadIdx.x & 63;
    const int wave = threadIdx.x >> 6;
    const int c = lane & 15;     // sample column
    const int g = lane >> 4;     // k/row group
    const int nbase = blockIdx.x * 64 + wave * 16;
    if (nbase >= N) return;

    // ---- loop-invariant weight fragments ----
    // W1^T as A: A[row=c][k=8g+j] = W1[k][m*16+c], zero for k>=4.
    bf16x8 a1[4];
#pragma unroll
    for (int m = 0; m < 4; ++m) {
        bf16x8 v = {0, 0, 0, 0, 0, 0, 0, 0};
        if (g == 0) {
#pragma unroll
            for (int j = 0; j < 4; ++j) v[j] = f2bf(W1[j * 64 + m * 16 + c]);
        }
        a1[m] = v;
    }
    // W2^T as A: A[row=c][k=32q+8g+j] = W2[k][m*16+c].
    bf16x8 a2[4][2];
#pragma unroll
    for (int m = 0; m < 4; ++m)
#pragma unroll
        for (int q = 0; q < 2; ++q) {
            bf16x8 v;
#pragma unroll
            for (int j = 0; j < 8; ++j)
                v[j] = f2bf(W2[(32 * q + 8 * g + j) * 64 + m * 16 + c]);
            a2[m][q] = v;
        }
    // Per-lane bias / W3 fragments in D layout (row = m*16+4g+r).
    f32x4 b1f[4], b2f[4], w3f[4];
#pragma unroll
    for (int m = 0; m < 4; ++m)
#pragma unroll
        for (int r = 0; r < 4; ++r) {
            b1f[m][r] = b1[m * 16 + 4 * g + r];
            b2f[m][r] = b2[m * 16 + 4 * g + r];
            w3f[m][r] = W3[m * 16 + 4 * g + r];
        }
    const float b3v = b3[0];

    // LDS addressing: logical byte (c*128 + hid*2), XOR-swizzled by ((c&7)<<4).
    char* hbase = (char*)&h1s[wave][0];
    const int swz = (c & 7) << 4;
    int woff[4], roff[2];
#pragma unroll
    for (int m = 0; m < 4; ++m) woff[m] = (c * 128 + m * 32 + g * 8) ^ swz;
#pragma unroll
    for (int q = 0; q < 2; ++q) roff[q] = (c * 128 + q * 64 + g * 16) ^ swz;

    // Features: all 4 lane-groups redundantly load sample c (coalescer merges).
    const float* fp = feat + (size_t)(nbase + c) * (TSTEPS * 3);
    float f0 = fp[0], f1 = fp[1], f2 = fp[2];
    float nf0 = 0.f, nf1 = 0.f, nf2 = 0.f;
    float delta = 0.0f;

    for (int t = 0; t < TSTEPS; ++t) {
        if (t + 1 < TSTEPS) {  // prefetch next step's features (latency off critical path)
            nf0 = fp[t * 3 + 3]; nf1 = fp[t * 3 + 4]; nf2 = fp[t * 3 + 5];
        }

        // x-frag (B of L1): rows 0..3 = [f0,f1,f2,delta]; rows>=4 don't care (A is 0 there).
        bf16x8 xb;
        xb[0] = f2bf(f0); xb[1] = f2bf(f1); xb[2] = f2bf(f2); xb[3] = f2bf(delta);
        xb[4] = 0; xb[5] = 0; xb[6] = 0; xb[7] = 0;

        // L1: h1 = relu(W1^T @ x + b1)
        f32x4 h1a[4];
#pragma unroll
        for (int m = 0; m < 4; ++m)
            h1a[m] = __builtin_amdgcn_mfma_f32_16x16x32_bf16(a1[m], xb, b1f[m], 0, 0, 0);

        // relu + pack to bf16 + LDS write ([c][m*16+4g..+3], 8B each)
#pragma unroll
        for (int m = 0; m < 4; ++m) {
            unsigned lo = ((unsigned)(unsigned short)f2bf(fmaxf(h1a[m][1], 0.f)) << 16)
                        | (unsigned short)f2bf(fmaxf(h1a[m][0], 0.f));
            unsigned hi = ((unsigned)(unsigned short)f2bf(fmaxf(h1a[m][3], 0.f)) << 16)
                        | (unsigned short)f2bf(fmaxf(h1a[m][2], 0.f));
            uint2 u; u.x = lo; u.y = hi;
            *(uint2*)(hbase + woff[m]) = u;
        }
        __asm__ volatile("" ::: "memory");  // keep reads after writes

        // B-frags of L2: lane reads h1[ k=32q+8g..+7 ][c] = 16B contiguous
        bf16x8 hb0 = *(const bf16x8*)(hbase + roff[0]);
        bf16x8 hb1 = *(const bf16x8*)(hbase + roff[1]);

        // L2: h2 = W2^T @ h1 + b2
        f32x4 acc[4];
#pragma unroll
        for (int m = 0; m < 4; ++m) {
            acc[m] = __builtin_amdgcn_mfma_f32_16x16x32_bf16(a2[m][0], hb0, b2f[m], 0, 0, 0);
            acc[m] = __builtin_amdgcn_mfma_f32_16x16x32_bf16(a2[m][1], hb1, acc[m], 0, 0, 0);
        }

        // L3: delta = relu(h2) . W3 + b3  (per-lane partial, reduce over g-groups)
        float p = 0.f;
#pragma unroll
        for (int m = 0; m < 4; ++m)
#pragma unroll
            for (int r = 0; r < 4; ++r)
                p = fmaf(fmaxf(acc[m][r], 0.f), w3f[m][r], p);
        p += __shfl_xor(p, 16, 64);
        p += __shfl_xor(p, 32, 64);
        delta = p + b3v;

        if (g == 0) dlt[wave][c * TSTEPS + t] = delta;
        f0 = nf0; f1 = nf1; f2 = nf2;
    }

    // Coalesced output: dlt layout [s][t] flat == out layout for 16 consecutive samples.
    float* ob = out + (size_t)nbase * TSTEPS;
#pragma unroll 1
    for (int i = lane; i < 16 * TSTEPS; i += 64) ob[i] = dlt[wave][i];
}

extern "C" void kernel_launch(void* const* d_in, const int* in_sizes, int n_in,
                              void* d_out, int out_size, void* d_ws, size_t ws_size,
                              hipStream_t stream) {
    const float* feat = (const float*)d_in[0];
    const float* W1   = (const float*)d_in[1];
    const float* b1   = (const float*)d_in[2];
    const float* W2   = (const float*)d_in[3];
    const float* b2   = (const float*)d_in[4];
    const float* W3   = (const float*)d_in[5];
    const float* b3   = (const float*)d_in[6];
    float* out = (float*)d_out;

    const int N = in_sizes[0] / (TSTEPS * 3);
    const int block = 256;                 // 4 waves x 16 samples = 64 samples/block
    const int grid = (N + 63) / 64;
    ffn_mfma<<<grid, block, 0, stream>>>(feat, W1, b1, W2, b2, W3, b3, out, N);
}